// Round 16
// baseline (542.774 us; speedup 1.0000x reference)
//
#include <hip/hip_runtime.h>
#include <hip/hip_bf16.h>
#include <cstdint>
#include <cstddef>

// Problem constants (fixed by setup_inputs)
#define NROWS_TOTAL 130320   // B*G
#define Gg 65160
#define Mm 40962
#define Dd 512
#define OUTD 128
#define RPB 64               // rows per block

typedef __attribute__((ext_vector_type(4))) float f32x4;
typedef __attribute__((ext_vector_type(2))) float f32x2;
typedef __attribute__((ext_vector_type(8))) short bf16x8;
typedef __attribute__((ext_vector_type(4))) unsigned short us4;
typedef __attribute__((ext_vector_type(8))) unsigned short us8;
typedef __attribute__((ext_vector_type(4))) unsigned int u32x4;

static __device__ __forceinline__ unsigned short f2bf(float x) {
  union { float f; unsigned u; } v; v.f = x;
  unsigned r = v.u + 0x7fffu + ((v.u >> 16) & 1u);
  return (unsigned short)(r >> 16);
}
static __device__ __forceinline__ float bf2f(unsigned short h) {
  return __uint_as_float(((unsigned)h) << 16);
}
// Pack two f32 -> two bf16 (RNE) in one instruction.
static __device__ __forceinline__ unsigned cvt_pk_bf16(float lo, float hi) {
  unsigned r;
  asm("v_cvt_pk_bf16_f32 %0, %1, %2" : "=v"(r) : "v"(lo), "v"(hi));
  return r;
}

// W1 (f32 [k=512][col=512]) -> W1F bf16 in MFMA-fragment order:
// element (col,k) at ((ct*16 + kk)*64 + kgrp*16 + lrow)*8 + j
__global__ void prep_w1(const float* __restrict__ W1, unsigned short* __restrict__ W1F) {
  const int t = blockIdx.x * 256 + threadIdx.x;     // 0..32767
  const int col = t >> 6, kg = t & 63;              // kg: group of 8 k's
  const int kk = kg >> 2, kgrp = kg & 3, kbase = kg * 8;
  us8 o;
  #pragma unroll
  for (int j = 0; j < 8; ++j) o[j] = f2bf(W1[(kbase + j) * Dd + col]);
  const int ct = col >> 4, lrow = col & 15;
  *(us8*)(W1F + ((((ct * 16 + kk) * 64) + kgrp * 16 + lrow) << 3)) = o;
}

// W2 (f32 [k=512][col=128]) -> W2F bf16, same fragment order (8 coltiles).
__global__ void prep_w2(const float* __restrict__ W2, unsigned short* __restrict__ W2F) {
  const int t = blockIdx.x * 256 + threadIdx.x;     // 0..8191
  const int col = t >> 6, kg = t & 63;
  const int kk = kg >> 2, kgrp = kg & 3, kbase = kg * 8;
  us8 o;
  #pragma unroll
  for (int j = 0; j < 8; ++j) o[j] = f2bf(W2[(kbase + j) * OUTD + col]);
  const int ct = col >> 4, lrow = col & 15;
  *(us8*)(W2F + ((((ct * 16 + kk) * 64) + kgrp * 16 + lrow) << 3)) = o;
}

// Stream-convert mesh f32 -> bf16 (NT loads keep the one-shot f32 stream out of L3)
__global__ void prep_mesh(const float* __restrict__ mesh, unsigned short* __restrict__ meshb,
                          int n4) {
  int i = blockIdx.x * blockDim.x + threadIdx.x;
  const int stride = gridDim.x * blockDim.x;
  for (; i < n4; i += stride) {
    const f32x4 v = __builtin_nontemporal_load(&((const f32x4*)mesh)[i]);
    us4 o;
    o.x = f2bf(v[0]); o.y = f2bf(v[1]); o.z = f2bf(v[2]); o.w = f2bf(v[3]);
    ((us4*)meshb)[i] = o;
  }
}

// Fused: gather -> GEMM1 -> LN -> SiLU -> GEMM2, split-gather interleave:
// gather rows [0,32) -> GEMM1 half0 -> gather rows [32,64) -> GEMM1 half1.
// __launch_bounds__(256) (no min-waves): LDS already limits to 2 blocks/CU,
// so the allocator may use up to ~256 VGPRs without occupancy loss.
__global__ __launch_bounds__(256) void fused_mlp(
    const unsigned short* __restrict__ meshb, // [2][M][512] bf16
    const int*   __restrict__ idx,    // [G][4]
    const float* __restrict__ wgt,    // [G][4]
    const float* __restrict__ b1,     // [512]
    const float* __restrict__ gamma,  // [512]
    const float* __restrict__ beta,   // [512]
    const float* __restrict__ b2,     // [128]
    const unsigned short* __restrict__ W1F, // fragment-ordered bf16
    const unsigned short* __restrict__ W2F, // fragment-ordered bf16
    float* __restrict__ out)          // [130320][128] f32
{
  __shared__ unsigned short Abuf[RPB][520]; // A tile, later reused for H
  __shared__ int   sOff[RPB][4];
  __shared__ float sWgt[RPB][4];
  __shared__ float psum[RPB][4];
  __shared__ float psq[RPB][4];

  const int tid  = threadIdx.x;
  const int wid  = tid >> 6;
  const int lane = tid & 63;
  const int lrow = lane & 15;   // A-row / B-col / C-col within fragment
  const int kgrp = lane >> 4;   // 0..3
  const int row0 = blockIdx.x * RPB;

  // ---------- Gather metadata preload (one (row,k) pair per thread) ----------
  {
    const int r = tid >> 2, k = tid & 3;
    const int row = row0 + r;
    int off = 0; float w = 0.f;
    if (row < NROWS_TOTAL) {
      const int b = (row >= Gg) ? 1 : 0;
      const int g = row - b * Gg;
      off = (b * Mm + idx[g * 4 + k]) * Dd;   // element offset, fits int32
      w = wgt[g * 4 + k];
    }
    sOff[r][k] = off;
    sWgt[r][k] = w;
  }
  __syncthreads();

  // Direct gather of 8 rows starting at rbase: load -> pk-fma -> LDS (bf16).
  auto gather8 = [&](int rbase) {
    #pragma unroll 4
    for (int i = 0; i < 8; ++i) {
      const int r = rbase + i;
      f32x2 acc[4];
      #pragma unroll
      for (int j = 0; j < 4; ++j) acc[j] = (f32x2){0.f, 0.f};
      #pragma unroll
      for (int k = 0; k < 4; ++k) {
        const int off = __builtin_amdgcn_readfirstlane(sOff[r][k]);
        union { int i; float f; } wu;
        wu.i = __builtin_amdgcn_readfirstlane(__float_as_int(sWgt[r][k]));
        const u32x4 u = *(const u32x4*)(meshb + (size_t)off + lane * 8);
        const f32x2 wv = (f32x2){wu.f, wu.f};
        #pragma unroll
        for (int j = 0; j < 4; ++j) {
          f32x2 p;
          p.x = __uint_as_float(u[j] << 16);
          p.y = __uint_as_float(u[j] & 0xFFFF0000u);
          acc[j] = p * wv + acc[j];
        }
      }
      u32x4 o;
      #pragma unroll
      for (int j = 0; j < 4; ++j) o[j] = cvt_pk_bf16(acc[j].x, acc[j].y);
      *(u32x4*)&Abuf[r][lane * 8] = o;
    }
  };

  f32x4 acc1[4][8];
  const int colbase1 = wid * 128;
  const unsigned short* w1w = W1F + ((size_t)(wid * 8) * 16 * 64 * 8);

  // Hoist +b1 coefficients: loads retire under GEMM1's MFMAs.
  float b1c[8];
  #pragma unroll
  for (int bc = 0; bc < 8; ++bc)
    b1c[bc] = b1[colbase1 + bc * 16 + lrow];

  // ---------- Phase A: gather rows [0,32) (wave w: rows w*8..w*8+7) ----------
  gather8(wid * 8);
  __syncthreads();

  // ---------- Phase B: GEMM1 on row-half 0 (ar = 0,1 -> rows 0..31) ----------
  #pragma unroll
  for (int i = 0; i < 2; ++i)
    #pragma unroll
    for (int j = 0; j < 8; ++j)
      acc1[i][j] = (f32x4){0.f, 0.f, 0.f, 0.f};
  {
    __builtin_amdgcn_s_setprio(1);
    for (int kk = 0; kk < 16; ++kk) {
      bf16x8 a[2];
      #pragma unroll
      for (int ar = 0; ar < 2; ++ar)
        a[ar] = *(const bf16x8*)&Abuf[ar * 16 + lrow][kk * 32 + kgrp * 8];
      #pragma unroll
      for (int bc = 0; bc < 8; ++bc) {
        const bf16x8 b = *(const bf16x8*)(w1w + (((bc * 16 + kk) * 64 + lane) << 3));
        #pragma unroll
        for (int ar = 0; ar < 2; ++ar)
          acc1[ar][bc] = __builtin_amdgcn_mfma_f32_16x16x32_bf16(a[ar], b, acc1[ar][bc], 0, 0, 0);
      }
    }
    __builtin_amdgcn_s_setprio(0);
  }

  // ---------- Phase C: gather rows [32,64) (disjoint from rows being read) ---
  gather8(32 + wid * 8);
  __syncthreads();

  // ---------- Phase D: GEMM1 on row-half 1 (ar = 2,3 -> rows 32..63) ----------
  #pragma unroll
  for (int i = 2; i < 4; ++i)
    #pragma unroll
    for (int j = 0; j < 8; ++j)
      acc1[i][j] = (f32x4){0.f, 0.f, 0.f, 0.f};
  {
    __builtin_amdgcn_s_setprio(1);
    for (int kk = 0; kk < 16; ++kk) {
      bf16x8 a[2];
      #pragma unroll
      for (int ar = 0; ar < 2; ++ar)
        a[ar] = *(const bf16x8*)&Abuf[32 + ar * 16 + lrow][kk * 32 + kgrp * 8];
      #pragma unroll
      for (int bc = 0; bc < 8; ++bc) {
        const bf16x8 b = *(const bf16x8*)(w1w + (((bc * 16 + kk) * 64 + lane) << 3));
        #pragma unroll
        for (int ar = 0; ar < 2; ++ar)
          acc1[2 + ar][bc] = __builtin_amdgcn_mfma_f32_16x16x32_bf16(a[ar], b, acc1[2 + ar][bc], 0, 0, 0);
      }
    }
    __builtin_amdgcn_s_setprio(0);
  }

  // ---------- +b1, per-row partial sums for LayerNorm ----------
  #pragma unroll
  for (int ar = 0; ar < 4; ++ar) {
    #pragma unroll
    for (int v = 0; v < 4; ++v) {
      float s = 0.f, q = 0.f;
      #pragma unroll
      for (int bc = 0; bc < 8; ++bc) {
        float x = acc1[ar][bc][v] + b1c[bc];
        acc1[ar][bc][v] = x;
        s += x;
        q += x * x;
      }
      #pragma unroll
      for (int off = 1; off < 16; off <<= 1) {
        s += __shfl_xor(s, off, 64);
        q += __shfl_xor(q, off, 64);
      }
      if (lrow == 0) {
        const int r = ar * 16 + kgrp * 4 + v;
        psum[r][wid] = s;
        psq[r][wid]  = q;
      }
    }
  }
  __syncthreads();  // all partials written; all waves done reading Abuf (A)

  // ---------- LayerNorm + SiLU, write H (bf16) into Abuf ----------
  float gmc[8], btc[8];
  #pragma unroll
  for (int bc = 0; bc < 8; ++bc) {
    const int col = colbase1 + bc * 16 + lrow;
    gmc[bc] = gamma[col];
    btc[bc] = beta[col];
  }
  #pragma unroll
  for (int ar = 0; ar < 4; ++ar) {
    #pragma unroll
    for (int v = 0; v < 4; ++v) {
      const int r = ar * 16 + kgrp * 4 + v;
      const float mu  = (psum[r][0] + psum[r][1] + psum[r][2] + psum[r][3]) * (1.f / 512.f);
      const float ms  = (psq[r][0]  + psq[r][1]  + psq[r][2]  + psq[r][3])  * (1.f / 512.f);
      const float var = ms - mu * mu;
      const float rstd = rsqrtf(var + 1e-5f);
      float y[8];
      #pragma unroll
      for (int bc = 0; bc < 8; ++bc) {
        const float x = acc1[ar][bc][v];
        const float t = (x - mu) * rstd * gmc[bc] + btc[bc];
        y[bc] = t * __builtin_amdgcn_rcpf(1.f + __expf(-t));   // SiLU, fast rcp
      }
      #pragma unroll
      for (int p = 0; p < 4; ++p) {
        const unsigned pk = cvt_pk_bf16(y[2 * p], y[2 * p + 1]);
        Abuf[r][colbase1 + (2 * p) * 16 + lrow]     = (unsigned short)pk;
        Abuf[r][colbase1 + (2 * p + 1) * 16 + lrow] = (unsigned short)(pk >> 16);
      }
    }
  }
  __syncthreads();

  // ---------- Phase 3: GEMM2 (64x128 = H[64x512] @ W2[512x128]) ----------
  f32x4 acc2[4][2];
  #pragma unroll
  for (int i = 0; i < 4; ++i)
    #pragma unroll
    for (int j = 0; j < 2; ++j)
      acc2[i][j] = (f32x4){0.f, 0.f, 0.f, 0.f};

  const int colbase2 = wid * 32;
  float b2c[2];
  #pragma unroll
  for (int bc = 0; bc < 2; ++bc)
    b2c[bc] = b2[colbase2 + bc * 16 + lrow];

  {
    const unsigned short* w2w = W2F + ((size_t)(wid * 2) * 16 * 64 * 8);
    __builtin_amdgcn_s_setprio(1);
    for (int kk = 0; kk < 16; ++kk) {
      bf16x8 a[4];
      #pragma unroll
      for (int ar = 0; ar < 4; ++ar)
        a[ar] = *(const bf16x8*)&Abuf[ar * 16 + lrow][kk * 32 + kgrp * 8];
      #pragma unroll
      for (int bc = 0; bc < 2; ++bc) {
        const bf16x8 b = *(const bf16x8*)(w2w + (((bc * 16 + kk) * 64 + lane) << 3));
        #pragma unroll
        for (int ar = 0; ar < 4; ++ar)
          acc2[ar][bc] = __builtin_amdgcn_mfma_f32_16x16x32_bf16(a[ar], b, acc2[ar][bc], 0, 0, 0);
      }
    }
    __builtin_amdgcn_s_setprio(0);
  }

  // ---------- Epilogue: +b2, NT store f32 ----------
  #pragma unroll
  for (int ar = 0; ar < 4; ++ar) {
    #pragma unroll
    for (int bc = 0; bc < 2; ++bc) {
      #pragma unroll
      for (int v = 0; v < 4; ++v) {
        const int r = ar * 16 + kgrp * 4 + v;
        const int row = row0 + r;
        if (row < NROWS_TOTAL)
          __builtin_nontemporal_store(acc2[ar][bc][v] + b2c[bc],
                                      &out[(size_t)row * OUTD + colbase2 + bc * 16 + lrow]);
      }
    }
  }
}

extern "C" void kernel_launch(void* const* d_in, const int* in_sizes, int n_in,
                              void* d_out, int out_size, void* d_ws, size_t ws_size,
                              hipStream_t stream) {
  const float* mesh  = (const float*)d_in[0];
  const int*   idx   = (const int*)d_in[1];
  const float* wgt   = (const float*)d_in[2];
  const float* W1    = (const float*)d_in[3];
  const float* b1    = (const float*)d_in[4];
  const float* gamma = (const float*)d_in[5];
  const float* beta  = (const float*)d_in[6];
  const float* W2    = (const float*)d_in[7];
  const float* b2    = (const float*)d_in[8];
  float* out = (float*)d_out;

  unsigned short* W1F   = (unsigned short*)d_ws;            // 512*512 bf16 = 512 KB
  unsigned short* W2F   = W1F + 512 * 512;                  // 128*512 bf16 = 128 KB
  unsigned short* meshb = W2F + 128 * 512;                  // 2*M*512 bf16 = 80 MiB

  prep_w1<<<128, 256, 0, stream>>>(W1, W1F);
  prep_w2<<<32, 256, 0, stream>>>(W2, W2F);
  const int n4 = 2 * Mm * Dd / 4;
  prep_mesh<<<4096, 256, 0, stream>>>(mesh, meshb, n4);

  const int nblocks = (NROWS_TOTAL + RPB - 1) / RPB;        // 2037
  fused_mlp<<<nblocks, 256, 0, stream>>>(meshb, idx, wgt, b1, gamma, beta, b2,
                                         W1F, W2F, out);
}

// Round 17
// 235.272 us; speedup vs baseline: 2.3070x; 2.3070x over previous
//
#include <hip/hip_runtime.h>
#include <hip/hip_bf16.h>
#include <cstdint>
#include <cstddef>

// Problem constants (fixed by setup_inputs)
#define NROWS_TOTAL 130320   // B*G
#define Gg 65160
#define Mm 40962
#define Dd 512
#define OUTD 128
#define RPB 64               // rows per block

typedef __attribute__((ext_vector_type(4))) float f32x4;
typedef __attribute__((ext_vector_type(2))) float f32x2;
typedef __attribute__((ext_vector_type(8))) short bf16x8;
typedef __attribute__((ext_vector_type(4))) unsigned short us4;
typedef __attribute__((ext_vector_type(8))) unsigned short us8;
typedef __attribute__((ext_vector_type(4))) unsigned int u32x4;

static __device__ __forceinline__ unsigned short f2bf(float x) {
  union { float f; unsigned u; } v; v.f = x;
  unsigned r = v.u + 0x7fffu + ((v.u >> 16) & 1u);
  return (unsigned short)(r >> 16);
}
// Pack two f32 -> two bf16 (RNE) in one instruction.
static __device__ __forceinline__ unsigned cvt_pk_bf16(float lo, float hi) {
  unsigned r;
  asm("v_cvt_pk_bf16_f32 %0, %1, %2" : "=v"(r) : "v"(lo), "v"(hi));
  return r;
}

// Combined prep: blocks [0,128) transpose W1 -> W1F (MFMA-fragment order),
// blocks [128,160) W2 -> W2F, blocks [160,4256) stream-convert mesh -> bf16.
// Fragment order: element (col,k) at ((ct*16 + kk)*64 + kgrp*16 + lrow)*8 + j
// so a wave reading fragment (ct,kk) does ONE contiguous 1KB load.
__global__ void prep_all(const float* __restrict__ W1, const float* __restrict__ W2,
                         const float* __restrict__ mesh,
                         unsigned short* __restrict__ W1F, unsigned short* __restrict__ W2F,
                         unsigned short* __restrict__ meshb, int n4) {
  const int blk = blockIdx.x;
  if (blk < 128) {
    const int t = blk * 256 + threadIdx.x;            // 0..32767
    const int col = t >> 6, kg = t & 63;
    const int kk = kg >> 2, kgrp = kg & 3, kbase = kg * 8;
    us8 o;
    #pragma unroll
    for (int j = 0; j < 8; ++j) o[j] = f2bf(W1[(kbase + j) * Dd + col]);
    const int ct = col >> 4, lrow = col & 15;
    *(us8*)(W1F + ((((ct * 16 + kk) * 64) + kgrp * 16 + lrow) << 3)) = o;
  } else if (blk < 160) {
    const int t = (blk - 128) * 256 + threadIdx.x;    // 0..8191
    const int col = t >> 6, kg = t & 63;
    const int kk = kg >> 2, kgrp = kg & 3, kbase = kg * 8;
    us8 o;
    #pragma unroll
    for (int j = 0; j < 8; ++j) o[j] = f2bf(W2[(kbase + j) * OUTD + col]);
    const int ct = col >> 4, lrow = col & 15;
    *(us8*)(W2F + ((((ct * 16 + kk) * 64) + kgrp * 16 + lrow) << 3)) = o;
  } else {
    int i = (blk - 160) * 256 + threadIdx.x;
    const int stride = 4096 * 256;
    for (; i < n4; i += stride) {
      const f32x4 v = __builtin_nontemporal_load(&((const f32x4*)mesh)[i]);
      us4 o;
      o.x = f2bf(v[0]); o.y = f2bf(v[1]); o.z = f2bf(v[2]); o.w = f2bf(v[3]);
      ((us4*)meshb)[i] = o;
    }
  }
}

// Fused: gather(bf16 mesh) -> GEMM1 -> LN -> SiLU -> GEMM2, R15 structure
// (single gather burst; no accumulators live across gather -> no spill).
// Block: 256 threads (4 waves), 64 rows. ~69KB LDS -> 2 blocks/CU.
__global__ __launch_bounds__(256, 2) void fused_mlp(
    const unsigned short* __restrict__ meshb, // [2][M][512] bf16
    const int*   __restrict__ idx,    // [G][4]
    const float* __restrict__ wgt,    // [G][4]
    const float* __restrict__ b1,     // [512]
    const float* __restrict__ gamma,  // [512]
    const float* __restrict__ beta,   // [512]
    const float* __restrict__ b2,     // [128]
    const unsigned short* __restrict__ W1F, // fragment-ordered bf16
    const unsigned short* __restrict__ W2F, // fragment-ordered bf16
    float* __restrict__ out)          // [130320][128] f32
{
  __shared__ unsigned short Abuf[RPB][520]; // A tile, later reused for H
  __shared__ int   sOff[RPB][4];
  __shared__ float sWgt[RPB][4];
  __shared__ float psum[RPB][4];
  __shared__ float psq[RPB][4];

  const int tid  = threadIdx.x;
  const int wid  = tid >> 6;
  const int lane = tid & 63;
  const int lrow = lane & 15;   // A-row / B-col / C-col within fragment
  const int kgrp = lane >> 4;   // 0..3
  const int row0 = blockIdx.x * RPB;

  // ---------- Gather metadata preload (one (row,k) pair per thread) ----------
  {
    const int r = tid >> 2, k = tid & 3;
    const int row = row0 + r;
    int off = 0; float w = 0.f;
    if (row < NROWS_TOTAL) {
      const int b = (row >= Gg) ? 1 : 0;
      const int g = row - b * Gg;
      off = (b * Mm + idx[g * 4 + k]) * Dd;   // element offset, fits int32
      w = wgt[g * 4 + k];
    }
    sOff[r][k] = off;
    sWgt[r][k] = w;
  }
  __syncthreads();

  // ---------- Phase 1: gather + weighted sum -> LDS (bf16) ----------
  // One wave per row: 64 lanes x 16B = 1KB bf16 row per load instruction.
  // Unpack is exact (lo = u<<16, hi = u&0xFFFF0000); float2 math -> v_pk_fma_f32.
  {
    const int rbase = wid * 16;
    #pragma unroll 4
    for (int i = 0; i < 16; ++i) {
      const int r = rbase + i;
      f32x2 acc[4];
      #pragma unroll
      for (int j = 0; j < 4; ++j) acc[j] = (f32x2){0.f, 0.f};
      #pragma unroll
      for (int k = 0; k < 4; ++k) {
        const int off = __builtin_amdgcn_readfirstlane(sOff[r][k]);
        union { int i; float f; } wu;
        wu.i = __builtin_amdgcn_readfirstlane(__float_as_int(sWgt[r][k]));
        const u32x4 u = *(const u32x4*)(meshb + (size_t)off + lane * 8);
        const f32x2 wv = (f32x2){wu.f, wu.f};
        #pragma unroll
        for (int j = 0; j < 4; ++j) {
          f32x2 p;
          p.x = __uint_as_float(u[j] << 16);
          p.y = __uint_as_float(u[j] & 0xFFFF0000u);
          acc[j] = p * wv + acc[j];
        }
      }
      u32x4 o;
      #pragma unroll
      for (int j = 0; j < 4; ++j) o[j] = cvt_pk_bf16(acc[j].x, acc[j].y);
      *(u32x4*)&Abuf[r][lane * 8] = o;
    }
  }
  __syncthreads();

  const int colbase1 = wid * 128;

  // Hoist +b1 coefficients; fold them into the accumulator init (saves the
  // +b1 pass; f32-exact up to summation order).
  float b1c[8];
  #pragma unroll
  for (int bc = 0; bc < 8; ++bc)
    b1c[bc] = b1[colbase1 + bc * 16 + lrow];

  // ---------- Phase 2: GEMM1 (64x512 = A[64x512] @ W1[512x512]) ----------
  // Wave w owns cols [w*128, w*128+128) = coltiles w*8 .. w*8+7.
  f32x4 acc1[4][8];
  #pragma unroll
  for (int i = 0; i < 4; ++i)
    #pragma unroll
    for (int j = 0; j < 8; ++j)
      acc1[i][j] = (f32x4){b1c[j], b1c[j], b1c[j], b1c[j]};

  {
    const unsigned short* w1w = W1F + ((size_t)(wid * 8) * 16 * 64 * 8);
    __builtin_amdgcn_s_setprio(1);
    for (int kk = 0; kk < 16; ++kk) {
      bf16x8 a[4];
      #pragma unroll
      for (int ar = 0; ar < 4; ++ar)
        a[ar] = *(const bf16x8*)&Abuf[ar * 16 + lrow][kk * 32 + kgrp * 8];
      #pragma unroll
      for (int bc = 0; bc < 8; ++bc) {
        const bf16x8 b = *(const bf16x8*)(w1w + (((bc * 16 + kk) * 64 + lane) << 3));
        #pragma unroll
        for (int ar = 0; ar < 4; ++ar)
          acc1[ar][bc] = __builtin_amdgcn_mfma_f32_16x16x32_bf16(a[ar], b, acc1[ar][bc], 0, 0, 0);
      }
    }
    __builtin_amdgcn_s_setprio(0);
  }

  // ---------- Per-row partial sums for LayerNorm (b1 already in acc) ----------
  #pragma unroll
  for (int ar = 0; ar < 4; ++ar) {
    #pragma unroll
    for (int v = 0; v < 4; ++v) {
      float s = 0.f, q = 0.f;
      #pragma unroll
      for (int bc = 0; bc < 8; ++bc) {
        const float x = acc1[ar][bc][v];
        s += x;
        q += x * x;
      }
      #pragma unroll
      for (int off = 1; off < 16; off <<= 1) {
        s += __shfl_xor(s, off, 64);
        q += __shfl_xor(q, off, 64);
      }
      if (lrow == 0) {
        const int r = ar * 16 + kgrp * 4 + v;
        psum[r][wid] = s;
        psq[r][wid]  = q;
      }
    }
  }
  __syncthreads();  // all partials written; all waves done reading Abuf (A)

  // ---------- LayerNorm + SiLU, write H (bf16) into Abuf ----------
  float gmc[8], btc[8];
  #pragma unroll
  for (int bc = 0; bc < 8; ++bc) {
    const int col = colbase1 + bc * 16 + lrow;
    gmc[bc] = gamma[col];
    btc[bc] = beta[col];
  }
  #pragma unroll
  for (int ar = 0; ar < 4; ++ar) {
    #pragma unroll
    for (int v = 0; v < 4; ++v) {
      const int r = ar * 16 + kgrp * 4 + v;
      const float mu  = (psum[r][0] + psum[r][1] + psum[r][2] + psum[r][3]) * (1.f / 512.f);
      const float ms  = (psq[r][0]  + psq[r][1]  + psq[r][2]  + psq[r][3])  * (1.f / 512.f);
      const float var = ms - mu * mu;
      const float rstd = rsqrtf(var + 1e-5f);
      float y[8];
      #pragma unroll
      for (int bc = 0; bc < 8; ++bc) {
        const float x = acc1[ar][bc][v];
        const float t = (x - mu) * rstd * gmc[bc] + btc[bc];
        y[bc] = t * __builtin_amdgcn_rcpf(1.f + __expf(-t));   // SiLU, fast rcp
      }
      #pragma unroll
      for (int p = 0; p < 4; ++p) {
        const unsigned pk = cvt_pk_bf16(y[2 * p], y[2 * p + 1]);
        Abuf[r][colbase1 + (2 * p) * 16 + lrow]     = (unsigned short)pk;
        Abuf[r][colbase1 + (2 * p + 1) * 16 + lrow] = (unsigned short)(pk >> 16);
      }
    }
  }
  __syncthreads();

  // ---------- Phase 3: GEMM2 (64x128 = H[64x512] @ W2[512x128]) ----------
  // Wave w owns cols [w*32, w*32+32) = coltiles w*2, w*2+1.
  const int colbase2 = wid * 32;
  float b2c[2];
  #pragma unroll
  for (int bc = 0; bc < 2; ++bc)
    b2c[bc] = b2[colbase2 + bc * 16 + lrow];

  f32x4 acc2[4][2];
  #pragma unroll
  for (int i = 0; i < 4; ++i)
    #pragma unroll
    for (int j = 0; j < 2; ++j)
      acc2[i][j] = (f32x4){b2c[j], b2c[j], b2c[j], b2c[j]};

  {
    const unsigned short* w2w = W2F + ((size_t)(wid * 2) * 16 * 64 * 8);
    __builtin_amdgcn_s_setprio(1);
    for (int kk = 0; kk < 16; ++kk) {
      bf16x8 a[4];
      #pragma unroll
      for (int ar = 0; ar < 4; ++ar)
        a[ar] = *(const bf16x8*)&Abuf[ar * 16 + lrow][kk * 32 + kgrp * 8];
      #pragma unroll
      for (int bc = 0; bc < 2; ++bc) {
        const bf16x8 b = *(const bf16x8*)(w2w + (((bc * 16 + kk) * 64 + lane) << 3));
        #pragma unroll
        for (int ar = 0; ar < 4; ++ar)
          acc2[ar][bc] = __builtin_amdgcn_mfma_f32_16x16x32_bf16(a[ar], b, acc2[ar][bc], 0, 0, 0);
      }
    }
    __builtin_amdgcn_s_setprio(0);
  }

  // ---------- Epilogue: NT store f32 (b2 already in acc) ----------
  #pragma unroll
  for (int ar = 0; ar < 4; ++ar) {
    #pragma unroll
    for (int bc = 0; bc < 2; ++bc) {
      #pragma unroll
      for (int v = 0; v < 4; ++v) {
        const int r = ar * 16 + kgrp * 4 + v;
        const int row = row0 + r;
        if (row < NROWS_TOTAL)
          __builtin_nontemporal_store(acc2[ar][bc][v],
                                      &out[(size_t)row * OUTD + colbase2 + bc * 16 + lrow]);
      }
    }
  }
}

extern "C" void kernel_launch(void* const* d_in, const int* in_sizes, int n_in,
                              void* d_out, int out_size, void* d_ws, size_t ws_size,
                              hipStream_t stream) {
  const float* mesh  = (const float*)d_in[0];
  const int*   idx   = (const int*)d_in[1];
  const float* wgt   = (const float*)d_in[2];
  const float* W1    = (const float*)d_in[3];
  const float* b1    = (const float*)d_in[4];
  const float* gamma = (const float*)d_in[5];
  const float* beta  = (const float*)d_in[6];
  const float* W2    = (const float*)d_in[7];
  const float* b2    = (const float*)d_in[8];
  float* out = (float*)d_out;

  unsigned short* W1F   = (unsigned short*)d_ws;            // 512*512 bf16 = 512 KB
  unsigned short* W2F   = W1F + 512 * 512;                  // 128*512 bf16 = 128 KB
  unsigned short* meshb = W2F + 128 * 512;                  // 2*M*512 bf16 = 80 MiB

  const int n4 = 2 * Mm * Dd / 4;
  prep_all<<<4256, 256, 0, stream>>>(W1, W2, mesh, W1F, W2F, meshb, n4);

  const int nblocks = (NROWS_TOTAL + RPB - 1) / RPB;        // 2037
  fused_mlp<<<nblocks, 256, 0, stream>>>(meshb, idx, wgt, b1, gamma, beta, b2,
                                         W1F, W2F, out);
}